// Round 2
// baseline (286.633 us; speedup 1.0000x reference)
//
#include <hip/hip_runtime.h>
#include <hip/hip_fp16.h>

#define FEATS 4
#define HID 32
#define BLK 256
#define CAP 64      // bucket slots per node; deg ~ Poisson(25), P(deg>=64) ~ 3.5e-9/node
#define PW 256      // nodes per dst-partition (power of 2)
#define PSHIFT 8
#define PCAP 8192   // edge slots per partition; E[edges/part]=6400, 22 sigma headroom
#define NPB 512     // blocks in partition pass
#define PBLK 1024   // threads in partition/local-csr kernels
#define MAXK 8      // edges register-cached per thread (e <= NPB*PBLK*MAXK)
#define MAXNP 512   // static LDS cap: requires n <= MAXNP*PW = 131072

static inline int cdiv(long long a, int b) { return (int)((a + b - 1) / b); }

// fp16 hidden-state fragment: 4 halves (8B). Planar tables: 16 cols = 32B/node.
struct __align__(8) half4v { __half2 a, b; };

typedef int vint4 __attribute__((ext_vector_type(4)));   // nt-loadable int4

// ---- zero int array --------------------------------------------------------
__global__ void k_zero_i(int* __restrict__ p, int n) {
    int i = blockIdx.x * blockDim.x + threadIdx.x;
    if (i < n) p[i] = 0;
}

// ---- pass B: partition edges by dst>>8, LDS-counted, chunk-reserved --------
__global__ void __launch_bounds__(PBLK, 4)
k_partition(const int* __restrict__ src, const int* __restrict__ dst,
            int* __restrict__ part_fill, unsigned int* __restrict__ part_edges,
            int e, int np) {
    __shared__ int lcnt[MAXNP];
    __shared__ int lbase[MAXNP];
    for (int p = threadIdx.x; p < np; p += blockDim.x) lcnt[p] = 0;
    __syncthreads();
    int chunk = (e + gridDim.x - 1) / gridDim.x;
    int lo = blockIdx.x * chunk;
    int hi = min(lo + chunk, e);
    unsigned pw[MAXK];
    int pp[MAXK];
#pragma unroll
    for (int k = 0; k < MAXK; k++) {
        int j = lo + threadIdx.x + k * (int)blockDim.x;
        if (j < hi) {
            int d = dst[j], s = src[j];
            int p = d >> PSHIFT;
            pp[k] = p;
            pw[k] = (unsigned)s | ((unsigned)(d & (PW - 1)) << 24);
            atomicAdd(&lcnt[p], 1);
        } else pp[k] = -1;
    }
    __syncthreads();
    for (int p = threadIdx.x; p < np; p += blockDim.x) {
        int c = lcnt[p];
        lbase[p] = c ? atomicAdd(&part_fill[p], c) : 0;
        lcnt[p] = 0;
    }
    __syncthreads();
#pragma unroll
    for (int k = 0; k < MAXK; k++) {
        if (pp[k] >= 0) {
            int p = pp[k];
            int pos = lbase[p] + atomicAdd(&lcnt[p], 1);
            if (pos < PCAP) part_edges[(size_t)p * PCAP + pos] = pw[k];
        }
    }
}

// ---- pass C: per-partition CSR via LDS atomics; emits deg + dinv + xn ------
__global__ void k_local_csr(const int* __restrict__ part_fill,
                            const unsigned int* __restrict__ part_edges,
                            const float4* __restrict__ x,
                            int* __restrict__ cnt_g, float* __restrict__ dinv,
                            float4* __restrict__ xn, int* __restrict__ bucket, int n) {
    __shared__ int cnt[PW];
    int p = blockIdx.x;
    if (threadIdx.x < PW) cnt[threadIdx.x] = 0;
    __syncthreads();
    int m = min(part_fill[p], PCAP);
    const unsigned int* pe = part_edges + (size_t)p * PCAP;
    int base_node = p << PSHIFT;
    for (int j = threadIdx.x; j < m; j += blockDim.x) {
        unsigned v = pe[j];
        int local = (int)(v >> 24);
        int s = (int)(v & 0xFFFFFFu);
        int pos = atomicAdd(&cnt[local], 1);  // LDS atomic
        if (pos < CAP) bucket[(size_t)(base_node + local) * CAP + pos] = s;
    }
    __syncthreads();
    if (threadIdx.x < PW) {
        int node = base_node + threadIdx.x;
        if (node < n) {
            int dg = cnt[threadIdx.x];
            cnt_g[node] = dg;
            float s = rsqrtf((float)(dg + 1));
            dinv[node] = s;
            float4 v = x[node];
            v.x *= s; v.y *= s; v.z *= s; v.w *= s;
            xn[node] = v;  // layer-1 pre-scaled input (fused — saves a pass)
        }
    }
}

// ---- dinv (fallback path only) ---------------------------------------------
__global__ void k_dinv(const int* __restrict__ deg, float* __restrict__ dinv, int n) {
    int i = blockIdx.x * blockDim.x + threadIdx.x;
    if (i < n) dinv[i] = rsqrtf((float)(deg[i] + 1));
}

// ---- fused layer-1: gather in 4-dim space + transform + layer-2 pre-scale --
// hn2 = (relu( [dinv*(xn[self]+sum xn[src])] @ W1 + b1) @ W2) * dinv
// -> written as two fp16 planar tables (cols 0-15 / 16-31), 3.2 MB each.
__global__ void k_gather4_f12(const int* __restrict__ cnt, const int* __restrict__ bucket,
                              const float4* __restrict__ xn, const float* __restrict__ dinv,
                              const float* __restrict__ W1, const float* __restrict__ b1,
                              const float* __restrict__ W2,
                              __half* __restrict__ hA, __half* __restrict__ hB, int n) {
    __shared__ float4 sW1[FEATS * 8];
    __shared__ float4 sB1[8];
    __shared__ float4 sW2[HID * 8];
    int tid = threadIdx.x;
    if (tid < FEATS * 8) sW1[tid] = ((const float4*)W1)[tid];
    if (tid < 8) sB1[tid] = ((const float4*)b1)[tid];
    sW2[tid] = ((const float4*)W2)[tid];  // blockDim.x == 256 == HID*8
    __syncthreads();
    int gid = blockIdx.x * blockDim.x + tid;
    int node = gid >> 3;
    int cq = gid & 7;
    if (node >= n) return;
    int dg = min(cnt[node], CAP);
    const int* row = bucket + (size_t)node * CAP;
    float4 acc = make_float4(0.f, 0.f, 0.f, 0.f);
    int j = cq;
    for (; j + 8 < dg; j += 16) {
        int s0 = __builtin_nontemporal_load(row + j);
        int s1 = __builtin_nontemporal_load(row + j + 8);
        float4 v0 = xn[s0];
        float4 v1 = xn[s1];
        acc.x += v0.x + v1.x; acc.y += v0.y + v1.y;
        acc.z += v0.z + v1.z; acc.w += v0.w + v1.w;
    }
    if (j < dg) {
        float4 v = xn[__builtin_nontemporal_load(row + j)];
        acc.x += v.x; acc.y += v.y; acc.z += v.z; acc.w += v.w;
    }
#pragma unroll
    for (int m = 1; m < 8; m <<= 1) {  // butterfly: all 8 lanes get the sum
        acc.x += __shfl_xor(acc.x, m, 8);
        acc.y += __shfl_xor(acc.y, m, 8);
        acc.z += __shfl_xor(acc.z, m, 8);
        acc.w += __shfl_xor(acc.w, m, 8);
    }
    float sc = dinv[node];
    float4 self = xn[node];
    float4 a;
    a.x = sc * (acc.x + self.x);
    a.y = sc * (acc.y + self.y);
    a.z = sc * (acc.z + self.z);
    a.w = sc * (acc.w + self.w);
    // y1 quad cq = relu(a @ W1 + b1)[4cq..4cq+3]
    float4 w0 = sW1[0 * 8 + cq], w1 = sW1[1 * 8 + cq];
    float4 w2 = sW1[2 * 8 + cq], w3 = sW1[3 * 8 + cq];
    float4 y = sB1[cq];
    y.x += a.x * w0.x + a.y * w1.x + a.z * w2.x + a.w * w3.x;
    y.y += a.x * w0.y + a.y * w1.y + a.z * w2.y + a.w * w3.y;
    y.z += a.x * w0.z + a.y * w1.z + a.z * w2.z + a.w * w3.z;
    y.w += a.x * w0.w + a.y * w1.w + a.z * w2.w + a.w * w3.w;
    y.x = fmaxf(y.x, 0.f); y.y = fmaxf(y.y, 0.f);
    y.z = fmaxf(y.z, 0.f); y.w = fmaxf(y.w, 0.f);
    // hn2 quad cq = (y_full @ W2)[4cq..4cq+3] * dinv; y_full across 8 lanes
    float4 o = make_float4(0.f, 0.f, 0.f, 0.f);
#pragma unroll
    for (int r = 0; r < 8; r++) {
        float4 v;
        v.x = __shfl(y.x, r, 8);
        v.y = __shfl(y.y, r, 8);
        v.z = __shfl(y.z, r, 8);
        v.w = __shfl(y.w, r, 8);
        float4 wa = sW2[(4 * r + 0) * 8 + cq];
        float4 wb = sW2[(4 * r + 1) * 8 + cq];
        float4 wc = sW2[(4 * r + 2) * 8 + cq];
        float4 wd = sW2[(4 * r + 3) * 8 + cq];
        o.x += v.x * wa.x + v.y * wb.x + v.z * wc.x + v.w * wd.x;
        o.y += v.x * wa.y + v.y * wb.y + v.z * wc.y + v.w * wd.y;
        o.z += v.x * wa.z + v.y * wb.z + v.z * wc.z + v.w * wd.z;
        o.w += v.x * wa.w + v.y * wb.w + v.z * wc.w + v.w * wd.w;
    }
    o.x *= sc; o.y *= sc; o.z *= sc; o.w *= sc;
    half4v st;
    st.a = __floats2half2_rn(o.x, o.y);
    st.b = __floats2half2_rn(o.z, o.w);
    unsigned long long u = *(const unsigned long long*)&st;
    __half* plane = (cq < 4) ? hA : hB;
    __builtin_nontemporal_store(u, (unsigned long long*)plane + (size_t)node * 4 + (cq & 3));
}

// ---- per-layer matmul + dinv pre-scale (fallback path) ---------------------
template <int K, int C>
__global__ void k_mm(const float* __restrict__ in, const float* __restrict__ W,
                     const float* __restrict__ dinv, float* __restrict__ hn, int n) {
    __shared__ float sW[K * C];
    for (int i = threadIdx.x; i < K * C; i += blockDim.x) sW[i] = W[i];
    __syncthreads();
    int gid = blockIdx.x * blockDim.x + threadIdx.x;
    int node = gid / C, c = gid % C;
    if (node >= n) return;
    float acc = 0.0f;
#pragma unroll
    for (int k = 0; k < K; k++) acc += in[node * K + k] * sW[k * C + c];
    hn[node * C + c] = acc * dinv[node];
}

#define ACC4(v) do { acc.x += (v).x; acc.y += (v).y; acc.z += (v).z; acc.w += (v).w; } while (0)

#define ACCH2(v) do { float2 f_ = __half22float2(v); acc.x += f_.x; acc.y += f_.y; } while (0)

// planar fp16 gather body: 8 lanes/node, lane cq reads half2 (cols 2cq,2cq+1)
// of a 16-col plane. Table = 3.2 MB -> L2-resident per XCD. Index reads nt.
#define GATHER_BODY_P(PLANE)                                                 \
    int dg = min(cnt[node], CAP);                                            \
    const __half2* hp = (const __half2*)(PLANE);                             \
    const int* row = bucket + (size_t)node * CAP;                            \
    float2 acc = __half22float2(hp[node * 8 + cq]);                          \
    int j = 0;                                                               \
    for (; j + 8 <= dg; j += 8) {                                            \
        vint4 sa = __builtin_nontemporal_load((const vint4*)(row + j));      \
        vint4 sb = __builtin_nontemporal_load((const vint4*)(row + j + 4));  \
        __half2 v0 = hp[sa.x * 8 + cq];                                      \
        __half2 v1 = hp[sa.y * 8 + cq];                                      \
        __half2 v2 = hp[sa.z * 8 + cq];                                      \
        __half2 v3 = hp[sa.w * 8 + cq];                                      \
        __half2 v4 = hp[sb.x * 8 + cq];                                      \
        __half2 v5 = hp[sb.y * 8 + cq];                                      \
        __half2 v6 = hp[sb.z * 8 + cq];                                      \
        __half2 v7 = hp[sb.w * 8 + cq];                                      \
        ACCH2(v0); ACCH2(v1); ACCH2(v2); ACCH2(v3);                          \
        ACCH2(v4); ACCH2(v5); ACCH2(v6); ACCH2(v7);                          \
    }                                                                        \
    if (j + 4 <= dg) {                                                       \
        vint4 s4 = __builtin_nontemporal_load((const vint4*)(row + j));      \
        __half2 v0 = hp[s4.x * 8 + cq];                                      \
        __half2 v1 = hp[s4.y * 8 + cq];                                      \
        __half2 v2 = hp[s4.z * 8 + cq];                                      \
        __half2 v3 = hp[s4.w * 8 + cq];                                      \
        ACCH2(v0); ACCH2(v1); ACCH2(v2); ACCH2(v3);                          \
        j += 4;                                                              \
    }                                                                        \
    for (; j < dg; j++) { ACCH2(hp[row[j] * 8 + cq]); }

// ---- layer-2/3 phase A: gather plane A, relu, stage y_A (fp16, n x 16) -----
__global__ void k_gfmmA(const int* __restrict__ cnt, const int* __restrict__ bucket,
                        const __half* __restrict__ hA, const float* __restrict__ dinv,
                        const float* __restrict__ bias, __half* __restrict__ yA, int n) {
    int gid = blockIdx.x * blockDim.x + threadIdx.x;
    int node = gid >> 3;
    int cq = gid & 7;
    if (node >= n) return;
    GATHER_BODY_P(hA)
    float sc = dinv[node];
    float2 b = ((const float2*)bias)[cq];   // cols 2cq, 2cq+1
    __half2 st = __floats2half2_rn(fmaxf(sc * acc.x + b.x, 0.f),
                                   fmaxf(sc * acc.y + b.y, 0.f));
    unsigned u = *(const unsigned*)&st;
    __builtin_nontemporal_store(u, (unsigned*)yA + (size_t)node * 8 + cq);
}

// ---- layer-2/3 phase B: gather plane B, combine y_A, MLP @ Wn, emit planes -
__global__ void k_gfmmB(const int* __restrict__ cnt, const int* __restrict__ bucket,
                        const __half* __restrict__ hB, const float* __restrict__ dinv,
                        const float* __restrict__ bias, const float* __restrict__ Wn,
                        const __half* __restrict__ yA,
                        __half* __restrict__ oA, __half* __restrict__ oB, int n) {
    __shared__ float4 sW[HID * 8];
    sW[threadIdx.x] = ((const float4*)Wn)[threadIdx.x];  // blockDim.x == 256
    __syncthreads();
    int gid = blockIdx.x * blockDim.x + threadIdx.x;
    int node = gid >> 3;
    int cq = gid & 7;
    if (node >= n) return;
    GATHER_BODY_P(hB)
    float sc = dinv[node];
    float2 b = ((const float2*)bias)[8 + cq];  // cols 16+2cq, 17+2cq
    float ybx = fmaxf(sc * acc.x + b.x, 0.f);
    float yby = fmaxf(sc * acc.y + b.y, 0.f);
    unsigned uy = __builtin_nontemporal_load((const unsigned*)yA + (size_t)node * 8 + cq);
    float2 ya = __half22float2(*(const __half2*)&uy);  // cols 2cq, 2cq+1
    float4 o = make_float4(0.f, 0.f, 0.f, 0.f);
#pragma unroll
    for (int r = 0; r < 8; r++) {
        float a0 = __shfl(ya.x, r, 8);   // y[2r]
        float a1 = __shfl(ya.y, r, 8);   // y[2r+1]
        float c0 = __shfl(ybx, r, 8);    // y[16+2r]
        float c1 = __shfl(yby, r, 8);    // y[17+2r]
        float4 w0 = sW[(2 * r + 0) * 8 + cq];
        float4 w1 = sW[(2 * r + 1) * 8 + cq];
        float4 w2 = sW[(16 + 2 * r) * 8 + cq];
        float4 w3 = sW[(17 + 2 * r) * 8 + cq];
        o.x += a0 * w0.x + a1 * w1.x + c0 * w2.x + c1 * w3.x;
        o.y += a0 * w0.y + a1 * w1.y + c0 * w2.y + c1 * w3.y;
        o.z += a0 * w0.z + a1 * w1.z + c0 * w2.z + c1 * w3.z;
        o.w += a0 * w0.w + a1 * w1.w + c0 * w2.w + c1 * w3.w;
    }
    o.x *= sc; o.y *= sc; o.z *= sc; o.w *= sc;
    half4v st;
    st.a = __floats2half2_rn(o.x, o.y);
    st.b = __floats2half2_rn(o.z, o.w);
    unsigned long long u = *(const unsigned long long*)&st;
    __half* plane = (cq < 4) ? oA : oB;
    __builtin_nontemporal_store(u, (unsigned long long*)plane + (size_t)node * 4 + (cq & 3));
}

// ---- layer-3 phase A of final head: partial dot over cols 0-15 -------------
__global__ void k_gfdotA(const int* __restrict__ cnt, const int* __restrict__ bucket,
                         const __half* __restrict__ hA, const float* __restrict__ dinv,
                         const float* __restrict__ bias, const float* __restrict__ W3,
                         float* __restrict__ pA, int n) {
    int gid = blockIdx.x * blockDim.x + threadIdx.x;
    int node = gid >> 3;
    int cq = gid & 7;
    if (node >= n) return;
    GATHER_BODY_P(hA)
    float sc = dinv[node];
    float2 b = ((const float2*)bias)[cq];
    float2 w = ((const float2*)W3)[cq];
    float p = fmaxf(sc * acc.x + b.x, 0.f) * w.x
            + fmaxf(sc * acc.y + b.y, 0.f) * w.y;
#pragma unroll
    for (int o = 4; o > 0; o >>= 1) p += __shfl_down(p, o, 8);
    if (cq == 0) pA[node] = p;
}

// ---- layer-3 phase B: cols 16-31 + combine -> hn4 (fp32 staged head) -------
__global__ void k_gfdotB(const int* __restrict__ cnt, const int* __restrict__ bucket,
                         const __half* __restrict__ hB, const float* __restrict__ dinv,
                         const float* __restrict__ bias, const float* __restrict__ W3,
                         const float* __restrict__ pA, float* __restrict__ hn4, int n) {
    int gid = blockIdx.x * blockDim.x + threadIdx.x;
    int node = gid >> 3;
    int cq = gid & 7;
    if (node >= n) return;
    GATHER_BODY_P(hB)
    float sc = dinv[node];
    float2 b = ((const float2*)bias)[8 + cq];
    float2 w = ((const float2*)W3)[8 + cq];
    float p = fmaxf(sc * acc.x + b.x, 0.f) * w.x
            + fmaxf(sc * acc.y + b.y, 0.f) * w.y;
#pragma unroll
    for (int o = 4; o > 0; o >>= 1) p += __shfl_down(p, o, 8);
    if (cq == 0) hn4[node] = (p + pA[node]) * sc;
}

// ---- scalar bucket gather (layer 4, fp32, 400 KB table: L2-resident) -------
__global__ void k_gather1b(const int* __restrict__ cnt, const int* __restrict__ bucket,
                           const float* __restrict__ hn, const float* __restrict__ dinv,
                           const float* __restrict__ b, float* __restrict__ out, int n) {
    int gid = blockIdx.x * blockDim.x + threadIdx.x;
    int node = gid >> 3;
    int lane = gid & 7;
    if (node >= n) return;
    int dg = min(cnt[node], CAP);
    const int* row = bucket + (size_t)node * CAP;
    float acc = (lane == 0) ? hn[node] : 0.0f;
    int j = lane;
    for (; j + 8 < dg; j += 16) {
        float a0 = hn[__builtin_nontemporal_load(row + j)];
        float a1 = hn[__builtin_nontemporal_load(row + j + 8)];
        acc += a0 + a1;
    }
    if (j < dg) acc += hn[__builtin_nontemporal_load(row + j)];
#pragma unroll
    for (int o = 4; o > 0; o >>= 1) acc += __shfl_down(acc, o, 8);
    if (lane == 0) out[node] = dinv[node] * acc + b[0];
}

// ======================= fallback (compact CSR, round-2) =====================
__global__ void k_deg_count(const int* __restrict__ dst, int* __restrict__ deg, int e) {
    int i = blockIdx.x * blockDim.x + threadIdx.x;
    if (i < e) atomicAdd(&deg[dst[i]], 1);
}

__global__ void k_block_scan(const int* __restrict__ deg, int* __restrict__ exc,
                             int* __restrict__ blk_sums, int n) {
    __shared__ int s[BLK];
    int i = blockIdx.x * BLK + threadIdx.x;
    int v = (i < n) ? deg[i] : 0;
    s[threadIdx.x] = v;
    __syncthreads();
    for (int off = 1; off < BLK; off <<= 1) {
        int t = (threadIdx.x >= (unsigned)off) ? s[threadIdx.x - off] : 0;
        __syncthreads();
        s[threadIdx.x] += t;
        __syncthreads();
    }
    if (i < n) exc[i] = s[threadIdx.x] - v;
    if (threadIdx.x == BLK - 1) blk_sums[blockIdx.x] = s[threadIdx.x];
}

__global__ void k_scan_sums(int* __restrict__ blk_sums, int nb) {
    __shared__ int s[1024];
    __shared__ int carry;
    if (threadIdx.x == 0) carry = 0;
    __syncthreads();
    for (int base = 0; base < nb; base += 1024) {
        int i = base + threadIdx.x;
        int v = (i < nb) ? blk_sums[i] : 0;
        s[threadIdx.x] = v;
        __syncthreads();
        for (int off = 1; off < 1024; off <<= 1) {
            int t = (threadIdx.x >= (unsigned)off) ? s[threadIdx.x - off] : 0;
            __syncthreads();
            s[threadIdx.x] += t;
            __syncthreads();
        }
        if (i < nb) blk_sums[i] = s[threadIdx.x] - v + carry;
        __syncthreads();
        if (threadIdx.x == 0) carry += s[1023];
        __syncthreads();
    }
}

__global__ void k_add_off(const int* __restrict__ exc, const int* __restrict__ blk_sums,
                          int* __restrict__ row_start, int* __restrict__ fill, int n) {
    int i = blockIdx.x * blockDim.x + threadIdx.x;
    if (i < n) {
        int rs = exc[i] + blk_sums[i / BLK];
        row_start[i] = rs;
        fill[i] = rs;
    }
}

__global__ void k_scatter(const int* __restrict__ src, const int* __restrict__ dst,
                          int* __restrict__ fill, int* __restrict__ csr_src, int e) {
    int i = blockIdx.x * blockDim.x + threadIdx.x;
    if (i < e) {
        int pos = atomicAdd(&fill[dst[i]], 1);
        csr_src[pos] = src[i];
    }
}

template <bool RELU>
__global__ void k_gather32(const int* __restrict__ row_start, const int* __restrict__ deg,
                           const int* __restrict__ csr_src, const float* __restrict__ hn,
                           const float* __restrict__ dinv, const float* __restrict__ bias,
                           float* __restrict__ y, int n) {
    int gid = blockIdx.x * blockDim.x + threadIdx.x;
    int node = gid >> 3;
    int cq = gid & 7;
    if (node >= n) return;
    int rs = row_start[node], dg = deg[node];
    const float4* hp = (const float4*)hn;
    float4 acc = hp[node * 8 + cq];
    for (int j = 0; j < dg; j++) {
        int s = csr_src[rs + j];
        float4 v = hp[s * 8 + cq];
        ACC4(v);
    }
    float sc = dinv[node];
    float4 b = ((const float4*)bias)[cq];
    float4 r;
    r.x = sc * acc.x + b.x; r.y = sc * acc.y + b.y;
    r.z = sc * acc.z + b.z; r.w = sc * acc.w + b.w;
    if (RELU) {
        r.x = fmaxf(r.x, 0.0f); r.y = fmaxf(r.y, 0.0f);
        r.z = fmaxf(r.z, 0.0f); r.w = fmaxf(r.w, 0.0f);
    }
    ((float4*)y)[node * 8 + cq] = r;
}

__global__ void k_gather1(const int* __restrict__ row_start, const int* __restrict__ deg,
                          const int* __restrict__ csr_src, const float* __restrict__ hn,
                          const float* __restrict__ dinv, const float* __restrict__ b,
                          float* __restrict__ out, int n) {
    int gid = blockIdx.x * blockDim.x + threadIdx.x;
    int node = gid >> 3;
    int lane = gid & 7;
    if (node >= n) return;
    int rs = row_start[node], dg = deg[node];
    float acc = (lane == 0) ? hn[node] : 0.0f;
    for (int j = lane; j < dg; j += 8) acc += hn[csr_src[rs + j]];
#pragma unroll
    for (int o = 4; o > 0; o >>= 1) acc += __shfl_down(acc, o, 8);
    if (lane == 0) out[node] = dinv[node] * acc + b[0];
}

extern "C" void kernel_launch(void* const* d_in, const int* in_sizes, int n_in,
                              void* d_out, int out_size, void* d_ws, size_t ws_size,
                              hipStream_t stream) {
    const float* x   = (const float*)d_in[0];
    const int*   ei  = (const int*)d_in[1];
    const float* W1  = (const float*)d_in[2];
    const float* b1  = (const float*)d_in[3];
    const float* W2  = (const float*)d_in[4];
    const float* b2  = (const float*)d_in[5];
    const float* W21 = (const float*)d_in[6];
    const float* b21 = (const float*)d_in[7];
    const float* W3  = (const float*)d_in[8];
    const float* b3  = (const float*)d_in[9];
    float* out = (float*)d_out;

    const int n = in_sizes[0] / FEATS;
    const int e = in_sizes[1] / 2;
    const int* src = ei;
    const int* dst = ei + e;
    const int nb = cdiv(n, BLK);
    const int np = cdiv(n, PW);

    auto align256 = [](size_t v) { return (v + 255) & ~(size_t)255; };
    const long long n8 = (long long)n * 8;

    size_t sz_cnt    = align256((size_t)n * 4);
    size_t sz_dinv   = align256((size_t)n * 4);
    size_t sz_f4     = align256((size_t)n * 16);
    size_t sz_bucket = align256((size_t)n * CAP * 4);
    size_t P         = align256((size_t)n * 32);   // one 16-col fp16 plane
    size_t S         = align256((size_t)n * 4);    // n x fp32 scalar
    size_t sz_planes = 5 * P + 2 * S;              // hA0,hB0,hA1,hB1,yA,pA,hn4
    size_t sz_part   = align256((size_t)np * PCAP * 4) + align256((size_t)np * 4);
    size_t region    = sz_planes > sz_part ? sz_planes : sz_part;
    size_t need = sz_cnt + sz_dinv + sz_f4 + sz_bucket + region;

    if (ws_size >= need && np <= MAXNP && (long long)e <= (long long)NPB * PBLK * MAXK) {
        char* ws = (char*)d_ws;
        size_t off = 0;
        int*    cnt_g  = (int*)(ws + off);    off += sz_cnt;
        float*  dinv   = (float*)(ws + off);  off += sz_dinv;
        float4* xn     = (float4*)(ws + off); off += sz_f4;
        int*    bucket = (int*)(ws + off);    off += sz_bucket;
        char*   reg    = ws + off;
        __half* hA0 = (__half*)reg;
        __half* hB0 = (__half*)(reg + P);
        __half* hA1 = (__half*)(reg + 2 * P);
        __half* hB1 = (__half*)(reg + 3 * P);
        __half* yA  = (__half*)(reg + 4 * P);
        float*  pA  = (float*)(reg + 5 * P);
        float*  hn4 = (float*)(reg + 5 * P + S);
        unsigned int* part_edges = (unsigned int*)reg;                       // dead after local_csr
        int* part_fill = (int*)(reg + align256((size_t)np * PCAP * 4));

        // ---- CSR build ----
        k_zero_i<<<cdiv(np, BLK), BLK, 0, stream>>>(part_fill, np);
        k_partition<<<NPB, PBLK, 0, stream>>>(src, dst, part_fill, part_edges, e, np);
        k_local_csr<<<np, PBLK, 0, stream>>>(part_fill, part_edges, (const float4*)x,
                                             cnt_g, dinv, xn, bucket, n);

        // ---- layer 1 fused: gather4 + W1 + relu + W2 + dinv -> fp16 planes ----
        k_gather4_f12<<<cdiv(n8, BLK), BLK, 0, stream>>>(cnt_g, bucket, xn, dinv,
                                                         W1, b1, W2, hA0, hB0, n);

        // ---- layer 2 (split gather: each phase's table is 3.2 MB, L2-resident) ----
        k_gfmmA<<<cdiv(n8, BLK), BLK, 0, stream>>>(cnt_g, bucket, hA0, dinv, b2, yA, n);
        k_gfmmB<<<cdiv(n8, BLK), BLK, 0, stream>>>(cnt_g, bucket, hB0, dinv, b2, W21,
                                                   yA, hA1, hB1, n);

        // ---- layer 3 (split gather + fused layer-4 staging dot) ----
        k_gfdotA<<<cdiv(n8, BLK), BLK, 0, stream>>>(cnt_g, bucket, hA1, dinv, b21, W3, pA, n);
        k_gfdotB<<<cdiv(n8, BLK), BLK, 0, stream>>>(cnt_g, bucket, hB1, dinv, b21, W3,
                                                    pA, hn4, n);

        // ---- layer 4 ----
        k_gather1b<<<cdiv(n8, BLK), BLK, 0, stream>>>(cnt_g, bucket, hn4, dinv, b3, out, n);
    } else {
        // ================= compact-CSR fallback (fp32 throughout) =================
        const long long nc = (long long)n * HID;
        char* ws = (char*)d_ws;
        size_t off = 0;
        int*   deg_i     = (int*)(ws + off);   off += align256((size_t)n * 4);
        int*   exc       = (int*)(ws + off);   off += align256((size_t)n * 4);
        int*   row_start = (int*)(ws + off);   off += align256((size_t)n * 4);
        int*   fill      = (int*)(ws + off);   off += align256((size_t)n * 4);
        int*   blk_sums  = (int*)(ws + off);   off += align256((size_t)nb * 4);
        float* dinv      = (float*)(ws + off); off += align256((size_t)n * 4);
        int*   csr_src   = (int*)(ws + off);   off += align256((size_t)e * 4);
        float* hn        = (float*)(ws + off); off += align256((size_t)n * HID * 4);
        float* yb        = (float*)(ws + off); off += align256((size_t)n * HID * 4);

        k_zero_i<<<nb, BLK, 0, stream>>>(deg_i, n);
        k_deg_count<<<cdiv(e, BLK), BLK, 0, stream>>>(dst, deg_i, e);
        k_dinv<<<nb, BLK, 0, stream>>>(deg_i, dinv, n);
        k_block_scan<<<nb, BLK, 0, stream>>>(deg_i, exc, blk_sums, n);
        k_scan_sums<<<1, 1024, 0, stream>>>(blk_sums, nb);
        k_add_off<<<nb, BLK, 0, stream>>>(exc, blk_sums, row_start, fill, n);
        k_scatter<<<cdiv(e, BLK), BLK, 0, stream>>>(src, dst, fill, csr_src, e);

        k_mm<FEATS, HID><<<cdiv(nc, BLK), BLK, 0, stream>>>(x, W1, dinv, hn, n);
        k_gather32<true><<<cdiv(n8, BLK), BLK, 0, stream>>>(row_start, deg_i, csr_src, hn, dinv, b1, yb, n);

        k_mm<HID, HID><<<cdiv(nc, BLK), BLK, 0, stream>>>(yb, W2, dinv, hn, n);
        k_gather32<true><<<cdiv(n8, BLK), BLK, 0, stream>>>(row_start, deg_i, csr_src, hn, dinv, b2, yb, n);

        k_mm<HID, HID><<<cdiv(nc, BLK), BLK, 0, stream>>>(yb, W21, dinv, hn, n);
        k_gather32<true><<<cdiv(n8, BLK), BLK, 0, stream>>>(row_start, deg_i, csr_src, hn, dinv, b21, yb, n);

        k_mm<HID, 1><<<cdiv(n, BLK), BLK, 0, stream>>>(yb, W3, dinv, hn, n);
        k_gather1<<<cdiv(n8, BLK), BLK, 0, stream>>>(row_start, deg_i, csr_src, hn, dinv, b3, out, n);
    }
}

// Round 3
// 240.698 us; speedup vs baseline: 1.1908x; 1.1908x over previous
//
#include <hip/hip_runtime.h>
#include <hip/hip_fp16.h>

#define FEATS 4
#define HID 32
#define BLK 256
#define CAP 64      // bucket slots per node; deg ~ Poisson(25), P(deg>=64) ~ 3.5e-9/node
#define PW 256      // nodes per dst-partition (power of 2)
#define PSHIFT 8
#define PCAP 8192   // edge slots per partition; E[edges/part]=6400, 22 sigma headroom
#define NPB 512     // blocks in partition pass
#define PBLK 1024   // threads in partition/local-csr kernels
#define MAXK 8      // edges register-cached per thread (e <= NPB*PBLK*MAXK)
#define MAXNP 512   // static LDS cap: requires n <= MAXNP*PW = 131072

static inline int cdiv(long long a, int b) { return (int)((a + b - 1) / b); }

// fp16 row fragments: half4v = 8B (8-lane kernels), half8v = 16B (4-lane kernels)
struct __align__(8)  half4v { __half2 a, b; };
struct __align__(16) half8v { __half2 a, b, c, d; };

typedef int vint4 __attribute__((ext_vector_type(4)));   // nt-loadable int4

// ---- zero int array --------------------------------------------------------
__global__ void k_zero_i(int* __restrict__ p, int n) {
    int i = blockIdx.x * blockDim.x + threadIdx.x;
    if (i < n) p[i] = 0;
}

// ---- pass B: partition edges by dst>>8, LDS-counted, chunk-reserved --------
__global__ void __launch_bounds__(PBLK, 4)
k_partition(const int* __restrict__ src, const int* __restrict__ dst,
            int* __restrict__ part_fill, unsigned int* __restrict__ part_edges,
            int e, int np) {
    __shared__ int lcnt[MAXNP];
    __shared__ int lbase[MAXNP];
    for (int p = threadIdx.x; p < np; p += blockDim.x) lcnt[p] = 0;
    __syncthreads();
    int chunk = (e + gridDim.x - 1) / gridDim.x;
    int lo = blockIdx.x * chunk;
    int hi = min(lo + chunk, e);
    unsigned pw[MAXK];
    int pp[MAXK];
#pragma unroll
    for (int k = 0; k < MAXK; k++) {
        int j = lo + threadIdx.x + k * (int)blockDim.x;
        if (j < hi) {
            int d = dst[j], s = src[j];
            int p = d >> PSHIFT;
            pp[k] = p;
            pw[k] = (unsigned)s | ((unsigned)(d & (PW - 1)) << 24);
            atomicAdd(&lcnt[p], 1);
        } else pp[k] = -1;
    }
    __syncthreads();
    for (int p = threadIdx.x; p < np; p += blockDim.x) {
        int c = lcnt[p];
        lbase[p] = c ? atomicAdd(&part_fill[p], c) : 0;
        lcnt[p] = 0;
    }
    __syncthreads();
#pragma unroll
    for (int k = 0; k < MAXK; k++) {
        if (pp[k] >= 0) {
            int p = pp[k];
            int pos = lbase[p] + atomicAdd(&lcnt[p], 1);
            if (pos < PCAP) part_edges[(size_t)p * PCAP + pos] = pw[k];
        }
    }
}

// ---- pass C: per-partition CSR via LDS atomics; emits deg + dinv + xn ------
__global__ void k_local_csr(const int* __restrict__ part_fill,
                            const unsigned int* __restrict__ part_edges,
                            const float4* __restrict__ x,
                            int* __restrict__ cnt_g, float* __restrict__ dinv,
                            float4* __restrict__ xn, int* __restrict__ bucket, int n) {
    __shared__ int cnt[PW];
    int p = blockIdx.x;
    if (threadIdx.x < PW) cnt[threadIdx.x] = 0;
    __syncthreads();
    int m = min(part_fill[p], PCAP);
    const unsigned int* pe = part_edges + (size_t)p * PCAP;
    int base_node = p << PSHIFT;
    for (int j = threadIdx.x; j < m; j += blockDim.x) {
        unsigned v = pe[j];
        int local = (int)(v >> 24);
        int s = (int)(v & 0xFFFFFFu);
        int pos = atomicAdd(&cnt[local], 1);  // LDS atomic
        if (pos < CAP) bucket[(size_t)(base_node + local) * CAP + pos] = s;
    }
    __syncthreads();
    if (threadIdx.x < PW) {
        int node = base_node + threadIdx.x;
        if (node < n) {
            int dg = cnt[threadIdx.x];
            cnt_g[node] = dg;
            float s = rsqrtf((float)(dg + 1));
            dinv[node] = s;
            float4 v = x[node];
            v.x *= s; v.y *= s; v.z *= s; v.w *= s;
            xn[node] = v;  // layer-1 pre-scaled input (fused — saves a pass)
        }
    }
}

// ---- dinv (fallback path only) ---------------------------------------------
__global__ void k_dinv(const int* __restrict__ deg, float* __restrict__ dinv, int n) {
    int i = blockIdx.x * blockDim.x + threadIdx.x;
    if (i < n) dinv[i] = rsqrtf((float)(deg[i] + 1));
}

// ---- fused layer-1: gather in 4-dim space + transform + layer-2 pre-scale --
// hn2 = (relu( [dinv*(xn[self]+sum xn[src])] @ W1 + b1) @ W2) * dinv  -> fp16
// 8 lanes/node; butterfly reduce so all lanes hold agg4; per-lane output quad.
__global__ void k_gather4_f12(const int* __restrict__ cnt, const int* __restrict__ bucket,
                              const float4* __restrict__ xn, const float* __restrict__ dinv,
                              const float* __restrict__ W1, const float* __restrict__ b1,
                              const float* __restrict__ W2, float* __restrict__ hn, int n) {
    __shared__ float4 sW1[FEATS * 8];
    __shared__ float4 sB1[8];
    __shared__ float4 sW2[HID * 8];
    int tid = threadIdx.x;
    if (tid < FEATS * 8) sW1[tid] = ((const float4*)W1)[tid];
    if (tid < 8) sB1[tid] = ((const float4*)b1)[tid];
    sW2[tid] = ((const float4*)W2)[tid];  // blockDim.x == 256 == HID*8
    __syncthreads();
    int gid = blockIdx.x * blockDim.x + tid;
    int node = gid >> 3;
    int cq = gid & 7;
    if (node >= n) return;
    int dg = min(cnt[node], CAP);
    const int* row = bucket + (size_t)node * CAP;
    float4 acc = make_float4(0.f, 0.f, 0.f, 0.f);
    int j = cq;
    for (; j + 8 < dg; j += 16) {
        int s0 = __builtin_nontemporal_load(row + j);
        int s1 = __builtin_nontemporal_load(row + j + 8);
        float4 v0 = xn[s0];
        float4 v1 = xn[s1];
        acc.x += v0.x + v1.x; acc.y += v0.y + v1.y;
        acc.z += v0.z + v1.z; acc.w += v0.w + v1.w;
    }
    if (j < dg) {
        float4 v = xn[__builtin_nontemporal_load(row + j)];
        acc.x += v.x; acc.y += v.y; acc.z += v.z; acc.w += v.w;
    }
#pragma unroll
    for (int m = 1; m < 8; m <<= 1) {  // butterfly: all 8 lanes get the sum
        acc.x += __shfl_xor(acc.x, m, 8);
        acc.y += __shfl_xor(acc.y, m, 8);
        acc.z += __shfl_xor(acc.z, m, 8);
        acc.w += __shfl_xor(acc.w, m, 8);
    }
    float sc = dinv[node];
    float4 self = xn[node];
    float4 a;
    a.x = sc * (acc.x + self.x);
    a.y = sc * (acc.y + self.y);
    a.z = sc * (acc.z + self.z);
    a.w = sc * (acc.w + self.w);
    // y1 quad cq = relu(a @ W1 + b1)[4cq..4cq+3]
    float4 w0 = sW1[0 * 8 + cq], w1 = sW1[1 * 8 + cq];
    float4 w2 = sW1[2 * 8 + cq], w3 = sW1[3 * 8 + cq];
    float4 y = sB1[cq];
    y.x += a.x * w0.x + a.y * w1.x + a.z * w2.x + a.w * w3.x;
    y.y += a.x * w0.y + a.y * w1.y + a.z * w2.y + a.w * w3.y;
    y.z += a.x * w0.z + a.y * w1.z + a.z * w2.z + a.w * w3.z;
    y.w += a.x * w0.w + a.y * w1.w + a.z * w2.w + a.w * w3.w;
    y.x = fmaxf(y.x, 0.f); y.y = fmaxf(y.y, 0.f);
    y.z = fmaxf(y.z, 0.f); y.w = fmaxf(y.w, 0.f);
    // hn2 quad cq = (y_full @ W2)[4cq..4cq+3] * dinv; y_full across 8 lanes
    float4 o = make_float4(0.f, 0.f, 0.f, 0.f);
#pragma unroll
    for (int r = 0; r < 8; r++) {
        float4 v;
        v.x = __shfl(y.x, r, 8);
        v.y = __shfl(y.y, r, 8);
        v.z = __shfl(y.z, r, 8);
        v.w = __shfl(y.w, r, 8);
        float4 wa = sW2[(4 * r + 0) * 8 + cq];
        float4 wb = sW2[(4 * r + 1) * 8 + cq];
        float4 wc = sW2[(4 * r + 2) * 8 + cq];
        float4 wd = sW2[(4 * r + 3) * 8 + cq];
        o.x += v.x * wa.x + v.y * wb.x + v.z * wc.x + v.w * wd.x;
        o.y += v.x * wa.y + v.y * wb.y + v.z * wc.y + v.w * wd.y;
        o.z += v.x * wa.z + v.y * wb.z + v.z * wc.z + v.w * wd.z;
        o.w += v.x * wa.w + v.y * wb.w + v.z * wc.w + v.w * wd.w;
    }
    o.x *= sc; o.y *= sc; o.z *= sc; o.w *= sc;
    half4v st;
    st.a = __floats2half2_rn(o.x, o.y);
    st.b = __floats2half2_rn(o.z, o.w);
    ((half4v*)hn)[node * 8 + cq] = st;   // plain store: keep table in L2
}

// ---- per-layer matmul + dinv pre-scale (fallback path) ---------------------
template <int K, int C>
__global__ void k_mm(const float* __restrict__ in, const float* __restrict__ W,
                     const float* __restrict__ dinv, float* __restrict__ hn, int n) {
    __shared__ float sW[K * C];
    for (int i = threadIdx.x; i < K * C; i += blockDim.x) sW[i] = W[i];
    __syncthreads();
    int gid = blockIdx.x * blockDim.x + threadIdx.x;
    int node = gid / C, c = gid % C;
    if (node >= n) return;
    float acc = 0.0f;
#pragma unroll
    for (int k = 0; k < K; k++) acc += in[node * K + k] * sW[k * C + c];
    hn[node * C + c] = acc * dinv[node];
}

#define ACC4(v) do { acc.x += (v).x; acc.y += (v).y; acc.z += (v).z; acc.w += (v).w; } while (0)

// fp16 16B-fragment accumulate: half8v -> two fp32 float4 accs
#define ACC8(v) do {                                                         \
        float2 f0_ = __half22float2((v).a);                                  \
        float2 f1_ = __half22float2((v).b);                                  \
        float2 f2_ = __half22float2((v).c);                                  \
        float2 f3_ = __half22float2((v).d);                                  \
        acc0.x += f0_.x; acc0.y += f0_.y; acc0.z += f1_.x; acc0.w += f1_.y;  \
        acc1.x += f2_.x; acc1.y += f2_.y; acc1.z += f3_.x; acc1.w += f3_.y;  \
    } while (0)

// 4-lane/node fp16 gather body: lane q in [0,4) holds cols 8q..8q+7 (16B).
// Per wave-instruction: 64 lanes x 16B = 1KiB, 16 edges in flight -> 2x MLP
// vs the 8-lane/8B layout, and half the gather instructions.
#define GATHER_BODY_H8()                                                     \
    int dg = min(cnt[node], CAP);                                            \
    const half8v* hp = (const half8v*)hn;                                    \
    const int* row = bucket + (size_t)node * CAP;                            \
    float4 acc0, acc1;                                                       \
    {                                                                        \
        half8v s_ = hp[node * 4 + q];                                        \
        float2 f0_ = __half22float2(s_.a), f1_ = __half22float2(s_.b);       \
        float2 f2_ = __half22float2(s_.c), f3_ = __half22float2(s_.d);       \
        acc0 = make_float4(f0_.x, f0_.y, f1_.x, f1_.y);                      \
        acc1 = make_float4(f2_.x, f2_.y, f3_.x, f3_.y);                      \
    }                                                                        \
    int j = 0;                                                               \
    for (; j + 8 <= dg; j += 8) {                                            \
        vint4 sa = __builtin_nontemporal_load((const vint4*)(row + j));      \
        vint4 sb = __builtin_nontemporal_load((const vint4*)(row + j + 4));  \
        half8v v0 = hp[sa.x * 4 + q];                                        \
        half8v v1 = hp[sa.y * 4 + q];                                        \
        half8v v2 = hp[sa.z * 4 + q];                                        \
        half8v v3 = hp[sa.w * 4 + q];                                        \
        half8v v4 = hp[sb.x * 4 + q];                                        \
        half8v v5 = hp[sb.y * 4 + q];                                        \
        half8v v6 = hp[sb.z * 4 + q];                                        \
        half8v v7 = hp[sb.w * 4 + q];                                        \
        ACC8(v0); ACC8(v1); ACC8(v2); ACC8(v3);                              \
        ACC8(v4); ACC8(v5); ACC8(v6); ACC8(v7);                              \
    }                                                                        \
    if (j + 4 <= dg) {                                                       \
        vint4 s4 = __builtin_nontemporal_load((const vint4*)(row + j));      \
        half8v v0 = hp[s4.x * 4 + q];                                        \
        half8v v1 = hp[s4.y * 4 + q];                                        \
        half8v v2 = hp[s4.z * 4 + q];                                        \
        half8v v3 = hp[s4.w * 4 + q];                                        \
        ACC8(v0); ACC8(v1); ACC8(v2); ACC8(v3);                              \
        j += 4;                                                              \
    }                                                                        \
    for (; j < dg; j++) { half8v v_ = hp[row[j] * 4 + q]; ACC8(v_); }

// compile-time component select (r is a constant under full unroll)
#define YSEL(r) ((r) == 0 ? y0.x : (r) == 1 ? y0.y : (r) == 2 ? y0.z : \
                 (r) == 3 ? y0.w : (r) == 4 ? y1.x : (r) == 5 ? y1.y : \
                 (r) == 6 ? y1.z : y1.w)

// ---- layer-2 gather (fp16, 4-lane) + fused layer-3 staging matmul ----------
__global__ void k_gather_fmm(const int* __restrict__ cnt, const int* __restrict__ bucket,
                             const float* __restrict__ hn, const float* __restrict__ dinv,
                             const float* __restrict__ bias, const float* __restrict__ Wn,
                             float* __restrict__ hn3, int n) {
    // sWa[r*4+q] = W[r][8q..8q+3], sWb[r*4+q] = W[r][8q+4..8q+7]
    __shared__ float4 sWa[HID * 4];
    __shared__ float4 sWb[HID * 4];
    int tid = threadIdx.x;
    {
        float4 f = ((const float4*)Wn)[tid];   // blockDim.x == 256 == HID*8
        int r = tid >> 3, c4 = tid & 7;
        if (c4 & 1) sWb[r * 4 + (c4 >> 1)] = f;
        else        sWa[r * 4 + (c4 >> 1)] = f;
    }
    __syncthreads();
    int gid = blockIdx.x * blockDim.x + tid;
    int node = gid >> 2;
    int q = gid & 3;
    if (node >= n) return;
    GATHER_BODY_H8()
    float sc = dinv[node];
    float4 b0 = ((const float4*)bias)[2 * q];
    float4 b1 = ((const float4*)bias)[2 * q + 1];
    float4 y0, y1;
    y0.x = fmaxf(sc * acc0.x + b0.x, 0.f); y0.y = fmaxf(sc * acc0.y + b0.y, 0.f);
    y0.z = fmaxf(sc * acc0.z + b0.z, 0.f); y0.w = fmaxf(sc * acc0.w + b0.w, 0.f);
    y1.x = fmaxf(sc * acc1.x + b1.x, 0.f); y1.y = fmaxf(sc * acc1.y + b1.y, 0.f);
    y1.z = fmaxf(sc * acc1.z + b1.z, 0.f); y1.w = fmaxf(sc * acc1.w + b1.w, 0.f);
    // o[8q..8q+7] = (y_full @ Wn) * dinv; y_full spread over 4 lanes
    float4 o0 = make_float4(0.f, 0.f, 0.f, 0.f);
    float4 o1 = make_float4(0.f, 0.f, 0.f, 0.f);
#pragma unroll
    for (int r = 0; r < HID; r++) {
        float yl = YSEL(r & 7);
        float yr = __shfl(yl, r >> 3, 4);
        float4 wa = sWa[r * 4 + q];
        float4 wb = sWb[r * 4 + q];
        o0.x += yr * wa.x; o0.y += yr * wa.y; o0.z += yr * wa.z; o0.w += yr * wa.w;
        o1.x += yr * wb.x; o1.y += yr * wb.y; o1.z += yr * wb.z; o1.w += yr * wb.w;
    }
    o0.x *= sc; o0.y *= sc; o0.z *= sc; o0.w *= sc;
    o1.x *= sc; o1.y *= sc; o1.z *= sc; o1.w *= sc;
    half8v st;
    st.a = __floats2half2_rn(o0.x, o0.y);
    st.b = __floats2half2_rn(o0.z, o0.w);
    st.c = __floats2half2_rn(o1.x, o1.y);
    st.d = __floats2half2_rn(o1.z, o1.w);
    ((half8v*)hn3)[node * 4 + q] = st;   // plain store: keep table in L2
}

// ---- layer-3 gather (fp16, 4-lane) + fused layer-4 staging dot -------------
__global__ void k_gather_fdot(const int* __restrict__ cnt, const int* __restrict__ bucket,
                              const float* __restrict__ hn, const float* __restrict__ dinv,
                              const float* __restrict__ bias, const float* __restrict__ W3,
                              float* __restrict__ hn4, int n) {
    int gid = blockIdx.x * blockDim.x + threadIdx.x;
    int node = gid >> 2;
    int q = gid & 3;
    if (node >= n) return;
    GATHER_BODY_H8()
    float sc = dinv[node];
    float4 b0 = ((const float4*)bias)[2 * q];
    float4 b1 = ((const float4*)bias)[2 * q + 1];
    float4 w0 = ((const float4*)W3)[2 * q];
    float4 w1 = ((const float4*)W3)[2 * q + 1];
    float p = fmaxf(sc * acc0.x + b0.x, 0.f) * w0.x
            + fmaxf(sc * acc0.y + b0.y, 0.f) * w0.y
            + fmaxf(sc * acc0.z + b0.z, 0.f) * w0.z
            + fmaxf(sc * acc0.w + b0.w, 0.f) * w0.w
            + fmaxf(sc * acc1.x + b1.x, 0.f) * w1.x
            + fmaxf(sc * acc1.y + b1.y, 0.f) * w1.y
            + fmaxf(sc * acc1.z + b1.z, 0.f) * w1.z
            + fmaxf(sc * acc1.w + b1.w, 0.f) * w1.w;
    p += __shfl_down(p, 2, 4);
    p += __shfl_down(p, 1, 4);
    if (q == 0) hn4[node] = p * sc;
}

// ---- scalar bucket gather (layer 4, fp32, 400 KB table: L2-resident) -------
__global__ void k_gather1b(const int* __restrict__ cnt, const int* __restrict__ bucket,
                           const float* __restrict__ hn, const float* __restrict__ dinv,
                           const float* __restrict__ b, float* __restrict__ out, int n) {
    int gid = blockIdx.x * blockDim.x + threadIdx.x;
    int node = gid >> 3;
    int lane = gid & 7;
    if (node >= n) return;
    int dg = min(cnt[node], CAP);
    const int* row = bucket + (size_t)node * CAP;
    float acc = (lane == 0) ? hn[node] : 0.0f;
    int j = lane;
    for (; j + 8 < dg; j += 16) {
        float a0 = hn[__builtin_nontemporal_load(row + j)];
        float a1 = hn[__builtin_nontemporal_load(row + j + 8)];
        acc += a0 + a1;
    }
    if (j < dg) acc += hn[__builtin_nontemporal_load(row + j)];
#pragma unroll
    for (int o = 4; o > 0; o >>= 1) acc += __shfl_down(acc, o, 8);
    if (lane == 0) out[node] = dinv[node] * acc + b[0];
}

// ======================= fallback (compact CSR, round-2) =====================
__global__ void k_deg_count(const int* __restrict__ dst, int* __restrict__ deg, int e) {
    int i = blockIdx.x * blockDim.x + threadIdx.x;
    if (i < e) atomicAdd(&deg[dst[i]], 1);
}

__global__ void k_block_scan(const int* __restrict__ deg, int* __restrict__ exc,
                             int* __restrict__ blk_sums, int n) {
    __shared__ int s[BLK];
    int i = blockIdx.x * BLK + threadIdx.x;
    int v = (i < n) ? deg[i] : 0;
    s[threadIdx.x] = v;
    __syncthreads();
    for (int off = 1; off < BLK; off <<= 1) {
        int t = (threadIdx.x >= (unsigned)off) ? s[threadIdx.x - off] : 0;
        __syncthreads();
        s[threadIdx.x] += t;
        __syncthreads();
    }
    if (i < n) exc[i] = s[threadIdx.x] - v;
    if (threadIdx.x == BLK - 1) blk_sums[blockIdx.x] = s[threadIdx.x];
}

__global__ void k_scan_sums(int* __restrict__ blk_sums, int nb) {
    __shared__ int s[1024];
    __shared__ int carry;
    if (threadIdx.x == 0) carry = 0;
    __syncthreads();
    for (int base = 0; base < nb; base += 1024) {
        int i = base + threadIdx.x;
        int v = (i < nb) ? blk_sums[i] : 0;
        s[threadIdx.x] = v;
        __syncthreads();
        for (int off = 1; off < 1024; off <<= 1) {
            int t = (threadIdx.x >= (unsigned)off) ? s[threadIdx.x - off] : 0;
            __syncthreads();
            s[threadIdx.x] += t;
            __syncthreads();
        }
        if (i < nb) blk_sums[i] = s[threadIdx.x] - v + carry;
        __syncthreads();
        if (threadIdx.x == 0) carry += s[1023];
        __syncthreads();
    }
}

__global__ void k_add_off(const int* __restrict__ exc, const int* __restrict__ blk_sums,
                          int* __restrict__ row_start, int* __restrict__ fill, int n) {
    int i = blockIdx.x * blockDim.x + threadIdx.x;
    if (i < n) {
        int rs = exc[i] + blk_sums[i / BLK];
        row_start[i] = rs;
        fill[i] = rs;
    }
}

__global__ void k_scatter(const int* __restrict__ src, const int* __restrict__ dst,
                          int* __restrict__ fill, int* __restrict__ csr_src, int e) {
    int i = blockIdx.x * blockDim.x + threadIdx.x;
    if (i < e) {
        int pos = atomicAdd(&fill[dst[i]], 1);
        csr_src[pos] = src[i];
    }
}

template <bool RELU>
__global__ void k_gather32(const int* __restrict__ row_start, const int* __restrict__ deg,
                           const int* __restrict__ csr_src, const float* __restrict__ hn,
                           const float* __restrict__ dinv, const float* __restrict__ bias,
                           float* __restrict__ y, int n) {
    int gid = blockIdx.x * blockDim.x + threadIdx.x;
    int node = gid >> 3;
    int cq = gid & 7;
    if (node >= n) return;
    int rs = row_start[node], dg = deg[node];
    const float4* hp = (const float4*)hn;
    float4 acc = hp[node * 8 + cq];
    for (int j = 0; j < dg; j++) {
        int s = csr_src[rs + j];
        float4 v = hp[s * 8 + cq];
        ACC4(v);
    }
    float sc = dinv[node];
    float4 b = ((const float4*)bias)[cq];
    float4 r;
    r.x = sc * acc.x + b.x; r.y = sc * acc.y + b.y;
    r.z = sc * acc.z + b.z; r.w = sc * acc.w + b.w;
    if (RELU) {
        r.x = fmaxf(r.x, 0.0f); r.y = fmaxf(r.y, 0.0f);
        r.z = fmaxf(r.z, 0.0f); r.w = fmaxf(r.w, 0.0f);
    }
    ((float4*)y)[node * 8 + cq] = r;
}

__global__ void k_gather1(const int* __restrict__ row_start, const int* __restrict__ deg,
                          const int* __restrict__ csr_src, const float* __restrict__ hn,
                          const float* __restrict__ dinv, const float* __restrict__ b,
                          float* __restrict__ out, int n) {
    int gid = blockIdx.x * blockDim.x + threadIdx.x;
    int node = gid >> 3;
    int lane = gid & 7;
    if (node >= n) return;
    int rs = row_start[node], dg = deg[node];
    float acc = (lane == 0) ? hn[node] : 0.0f;
    for (int j = lane; j < dg; j += 8) acc += hn[csr_src[rs + j]];
#pragma unroll
    for (int o = 4; o > 0; o >>= 1) acc += __shfl_down(acc, o, 8);
    if (lane == 0) out[node] = dinv[node] * acc + b[0];
}

extern "C" void kernel_launch(void* const* d_in, const int* in_sizes, int n_in,
                              void* d_out, int out_size, void* d_ws, size_t ws_size,
                              hipStream_t stream) {
    const float* x   = (const float*)d_in[0];
    const int*   ei  = (const int*)d_in[1];
    const float* W1  = (const float*)d_in[2];
    const float* b1  = (const float*)d_in[3];
    const float* W2  = (const float*)d_in[4];
    const float* b2  = (const float*)d_in[5];
    const float* W21 = (const float*)d_in[6];
    const float* b21 = (const float*)d_in[7];
    const float* W3  = (const float*)d_in[8];
    const float* b3  = (const float*)d_in[9];
    float* out = (float*)d_out;

    const int n = in_sizes[0] / FEATS;
    const int e = in_sizes[1] / 2;
    const int* src = ei;
    const int* dst = ei + e;
    const int nb = cdiv(n, BLK);
    const int np = cdiv(n, PW);

    auto align256 = [](size_t v) { return (v + 255) & ~(size_t)255; };
    const long long n8 = (long long)n * 8;
    const long long n4 = (long long)n * 4;

    size_t sz_cnt    = align256((size_t)n * 4);
    size_t sz_dinv   = align256((size_t)n * 4);
    size_t sz_f4     = align256((size_t)n * 16);
    size_t sz_bucket = align256((size_t)n * CAP * 4);
    size_t sz_hn     = align256((size_t)n * HID * 4);  // fp32-sized regions kept (aliasing)
    size_t sz_part   = align256((size_t)np * PCAP * 4) + align256((size_t)np * 4);
    size_t region    = 2 * sz_hn > sz_part ? 2 * sz_hn : sz_part;
    size_t need = sz_cnt + sz_dinv + sz_f4 + sz_bucket + region;

    if (ws_size >= need && np <= MAXNP && (long long)e <= (long long)NPB * PBLK * MAXK) {
        char* ws = (char*)d_ws;
        size_t off = 0;
        int*    cnt_g  = (int*)(ws + off);    off += sz_cnt;
        float*  dinv   = (float*)(ws + off);  off += sz_dinv;
        float4* xn     = (float4*)(ws + off); off += sz_f4;
        int*    bucket = (int*)(ws + off);    off += sz_bucket;
        char*   reg    = ws + off;
        float* hn = (float*)reg;            // hn2 (fp16), later hn4 (fp32 scalar head)
        float* yb = (float*)(reg + sz_hn);  // hn3 (fp16)
        unsigned int* part_edges = (unsigned int*)reg;                       // aliases hn
        int* part_fill = (int*)(reg + align256((size_t)np * PCAP * 4));      // aliases yb head

        // ---- CSR build ----
        k_zero_i<<<cdiv(np, BLK), BLK, 0, stream>>>(part_fill, np);
        k_partition<<<NPB, PBLK, 0, stream>>>(src, dst, part_fill, part_edges, e, np);
        k_local_csr<<<np, PBLK, 0, stream>>>(part_fill, part_edges, (const float4*)x,
                                             cnt_g, dinv, xn, bucket, n);

        // ---- layer 1+2-staging fused: gather4 + W1 + relu + W2 + dinv -> fp16 ----
        k_gather4_f12<<<cdiv(n8, BLK), BLK, 0, stream>>>(cnt_g, bucket, xn, dinv,
                                                         W1, b1, W2, hn, n);

        // ---- layers 2-4 (fp16 hidden gathers, 4-lane/16B, fp32 accumulate) ----
        k_gather_fmm<<<cdiv(n4, BLK), BLK, 0, stream>>>(cnt_g, bucket, hn, dinv, b2, W21, yb, n);
        k_gather_fdot<<<cdiv(n4, BLK), BLK, 0, stream>>>(cnt_g, bucket, yb, dinv, b21, W3, hn, n);
        k_gather1b<<<cdiv(n8, BLK), BLK, 0, stream>>>(cnt_g, bucket, hn, dinv, b3, out, n);
    } else {
        // ================= compact-CSR fallback (fp32 throughout) =================
        const long long nc = (long long)n * HID;
        char* ws = (char*)d_ws;
        size_t off = 0;
        int*   deg_i     = (int*)(ws + off);   off += align256((size_t)n * 4);
        int*   exc       = (int*)(ws + off);   off += align256((size_t)n * 4);
        int*   row_start = (int*)(ws + off);   off += align256((size_t)n * 4);
        int*   fill      = (int*)(ws + off);   off += align256((size_t)n * 4);
        int*   blk_sums  = (int*)(ws + off);   off += align256((size_t)nb * 4);
        float* dinv      = (float*)(ws + off); off += align256((size_t)n * 4);
        int*   csr_src   = (int*)(ws + off);   off += align256((size_t)e * 4);
        float* hn        = (float*)(ws + off); off += align256((size_t)n * HID * 4);
        float* yb        = (float*)(ws + off); off += align256((size_t)n * HID * 4);

        k_zero_i<<<nb, BLK, 0, stream>>>(deg_i, n);
        k_deg_count<<<cdiv(e, BLK), BLK, 0, stream>>>(dst, deg_i, e);
        k_dinv<<<nb, BLK, 0, stream>>>(deg_i, dinv, n);
        k_block_scan<<<nb, BLK, 0, stream>>>(deg_i, exc, blk_sums, n);
        k_scan_sums<<<1, 1024, 0, stream>>>(blk_sums, nb);
        k_add_off<<<nb, BLK, 0, stream>>>(exc, blk_sums, row_start, fill, n);
        k_scatter<<<cdiv(e, BLK), BLK, 0, stream>>>(src, dst, fill, csr_src, e);

        k_mm<FEATS, HID><<<cdiv(nc, BLK), BLK, 0, stream>>>(x, W1, dinv, hn, n);
        k_gather32<true><<<cdiv(n8, BLK), BLK, 0, stream>>>(row_start, deg_i, csr_src, hn, dinv, b1, yb, n);

        k_mm<HID, HID><<<cdiv(nc, BLK), BLK, 0, stream>>>(yb, W2, dinv, hn, n);
        k_gather32<true><<<cdiv(n8, BLK), BLK, 0, stream>>>(row_start, deg_i, csr_src, hn, dinv, b2, yb, n);

        k_mm<HID, HID><<<cdiv(nc, BLK), BLK, 0, stream>>>(yb, W21, dinv, hn, n);
        k_gather32<true><<<cdiv(n8, BLK), BLK, 0, stream>>>(row_start, deg_i, csr_src, hn, dinv, b21, yb, n);

        k_mm<HID, 1><<<cdiv(n, BLK), BLK, 0, stream>>>(yb, W3, dinv, hn, n);
        k_gather1<<<cdiv(n8, BLK), BLK, 0, stream>>>(row_start, deg_i, csr_src, hn, dinv, b3, out, n);
    }
}